// Round 1
// baseline (461.767 us; speedup 1.0000x reference)
//
#include <hip/hip_runtime.h>
#include <hip/hip_bf16.h>

// Problem constants (reference: B=2, S=2048, H=16, D=128, fp32, causal, RoPE interleaved)
#define B_  2
#define S_  2048
#define H_  16
#define D_  128
#define BQ  64          // q rows per block (16 per wave x 4 waves)
#define BK  64          // keys per tile
#define DP  136         // D + 8 bf16 pad (row stride 272 B, 16B-aligned, 2-way LDS conflict)
#define BKP 72          // BK + 8 pad
#define SH  (H_ * D_)   // 2048: seq stride in q/k/v

typedef __attribute__((ext_vector_type(8))) short bf16x8;   // MFMA A/B frag (8 bf16)
typedef __attribute__((ext_vector_type(4))) float f32x4;    // MFMA C/D frag

// fp32 -> bf16 round-to-nearest-even, cheap bit version
__device__ __forceinline__ ushort f2bf(float x) {
  union { float f; unsigned u; } c; c.f = x;
  unsigned u = c.u;
  return (ushort)((u + 0x7FFFu + ((u >> 16) & 1u)) >> 16);
}

__global__ __launch_bounds__(256, 2)
void fattn_rope(const float* __restrict__ qg, const float* __restrict__ kg,
                const float* __restrict__ vg, const float* __restrict__ fg,
                float* __restrict__ og) {
  __shared__ __align__(16) ushort sK[BK][DP];     // rope(K) bf16, row-major [key][dim]
  __shared__ __align__(16) ushort sVt[D_][BKP];   // V bf16 TRANSPOSED [dim][key]
  __shared__ __align__(16) union {
    ushort q[BQ][DP];        // rope(Q)*scale*log2e bf16 (used once at start)
    ushort p[4][16][BKP];    // per-wave P tile bf16 (reuses Q space)
  } uQP;

  const int qt   = (int)gridDim.x - 1 - (int)blockIdx.x;  // heavy (large qt) blocks first
  const int h    = blockIdx.y;
  const int b    = blockIdx.z;
  const int q0   = qt * BQ;
  const int tid  = threadIdx.x;
  const int wv   = tid >> 6;     // wave 0..3 -> q rows [wv*16, wv*16+16)
  const int lane = tid & 63;
  const int l15  = lane & 15;
  const int quad = lane >> 4;

  const float* qb = qg + (size_t)b * S_ * SH + (size_t)h * D_;
  const float* kb = kg + (size_t)b * S_ * SH + (size_t)h * D_;
  const float* vb = vg + (size_t)b * S_ * SH + (size_t)h * D_;

  // fold 1/sqrt(D) * log2(e) into Q so softmax is exp2-domain
  const float QS = 0.08838834764831845f * 1.4426950408889634f;

  // ---------------- stage Q: RoPE + scale, fp32 -> bf16 ----------------
  for (int i = tid; i < BQ * (D_ / 2); i += 256) {
    const int row = i >> 6;        // 64 pairs per row
    const int pr  = i & 63;
    const int s   = q0 + row;
    const float2 x = *(const float2*)(qb + (size_t)s * SH + 2 * pr);
    const float2 f = *(const float2*)(fg + (size_t)s * D_ + 2 * pr);
    const float o0 = (f.x * x.x - f.y * x.y) * QS;
    const float o1 = (f.y * x.x + f.x * x.y) * QS;
    const unsigned pk = (unsigned)f2bf(o0) | ((unsigned)f2bf(o1) << 16);
    *(unsigned*)&uQP.q[row][2 * pr] = pk;
  }
  __syncthreads();

  // Q fragments (A-operand: m = l15 = q-row-in-wave, k = quad*8+j), held for whole kernel
  bf16x8 afq[4];
  #pragma unroll
  for (int ks = 0; ks < 4; ks++)
    afq[ks] = *(const bf16x8*)&uQP.q[wv * 16 + l15][ks * 32 + quad * 8];
  __syncthreads();   // uQP space now reused as P buffer

  // online-softmax state: lane covers rows quad*4+r (replicated across the 16 lanes of a quad)
  float m_i[4], l_i[4];
  f32x4 o_acc[8];    // O tile: row = quad*4+r, col(dim) = dt*16 + l15
  #pragma unroll
  for (int r = 0; r < 4; r++) { m_i[r] = -1e30f; l_i[r] = 0.0f; }
  #pragma unroll
  for (int dt = 0; dt < 8; dt++) o_acc[dt] = (f32x4)0.0f;

  for (int kt = 0; kt <= qt; kt++) {
    const int k0 = kt * BK;

    // ---- stage K tile: RoPE fp32 -> bf16, row-major ----
    for (int i = tid; i < BK * (D_ / 2); i += 256) {
      const int row = i >> 6;
      const int pr  = i & 63;
      const int s   = k0 + row;
      const float2 x = *(const float2*)(kb + (size_t)s * SH + 2 * pr);
      const float2 f = *(const float2*)(fg + (size_t)s * D_ + 2 * pr);
      const float o0 = f.x * x.x - f.y * x.y;
      const float o1 = f.y * x.x + f.x * x.y;
      const unsigned pk = (unsigned)f2bf(o0) | ((unsigned)f2bf(o1) << 16);
      *(unsigned*)&sK[row][2 * pr] = pk;
    }
    // ---- stage V tile transposed: Vt[dim][key] bf16 ----
    {
      const int d2  = (tid & 63) * 2;   // this thread's dim pair
      const int grp = tid >> 6;         // 16 keys per group
      #pragma unroll
      for (int c = 0; c < 2; c++) {
        const int kk = grp * 16 + c * 8;
        union { ushort u[8]; bf16x8 v; } p0, p1;
        #pragma unroll
        for (int j = 0; j < 8; j++) {
          const float2 xv = *(const float2*)(vb + (size_t)(k0 + kk + j) * SH + d2);
          p0.u[j] = f2bf(xv.x);
          p1.u[j] = f2bf(xv.y);
        }
        *(bf16x8*)&sVt[d2][kk]     = p0.v;
        *(bf16x8*)&sVt[d2 + 1][kk] = p1.v;
      }
    }
    __syncthreads();

    // ---- S = (Q*scale*log2e) · K^T : 16x64 per wave ----
    f32x4 sc[4];
    #pragma unroll
    for (int nt = 0; nt < 4; nt++) {
      f32x4 acc = (f32x4)0.0f;
      #pragma unroll
      for (int ks = 0; ks < 4; ks++) {
        const bf16x8 bk_ = *(const bf16x8*)&sK[nt * 16 + l15][ks * 32 + quad * 8];
        acc = __builtin_amdgcn_mfma_f32_16x16x32_bf16(afq[ks], bk_, acc, 0, 0, 0);
      }
      sc[nt] = acc;
    }

    // ---- causal mask (diagonal tile only; k0==q0 there) ----
    if (kt == qt) {
      #pragma unroll
      for (int nt = 0; nt < 4; nt++) {
        const int col = nt * 16 + l15;
        #pragma unroll
        for (int r = 0; r < 4; r++) {
          const int row = wv * 16 + quad * 4 + r;
          if (col > row) sc[nt][r] = -1e30f;
        }
      }
    }

    // ---- online softmax (exp2 domain) ----
    float mnew[4], alpha[4];
    #pragma unroll
    for (int r = 0; r < 4; r++) {
      float mx = fmaxf(fmaxf(sc[0][r], sc[1][r]), fmaxf(sc[2][r], sc[3][r]));
      mx = fmaxf(mx, __shfl_xor(mx, 1));
      mx = fmaxf(mx, __shfl_xor(mx, 2));
      mx = fmaxf(mx, __shfl_xor(mx, 4));
      mx = fmaxf(mx, __shfl_xor(mx, 8));
      mnew[r]  = fmaxf(m_i[r], mx);
      alpha[r] = __builtin_amdgcn_exp2f(m_i[r] - mnew[r]);  // 0 on first tile
      m_i[r]   = mnew[r];
    }
    float rs[4] = {0.0f, 0.0f, 0.0f, 0.0f};
    #pragma unroll
    for (int nt = 0; nt < 4; nt++) {
      #pragma unroll
      for (int r = 0; r < 4; r++) {
        const float p = __builtin_amdgcn_exp2f(sc[nt][r] - mnew[r]);
        sc[nt][r] = p;
        rs[r] += p;
      }
    }
    #pragma unroll
    for (int r = 0; r < 4; r++) {
      float t = rs[r];
      t += __shfl_xor(t, 1);
      t += __shfl_xor(t, 2);
      t += __shfl_xor(t, 4);
      t += __shfl_xor(t, 8);
      l_i[r] = l_i[r] * alpha[r] + t;
    }

    // ---- P: C-layout -> LDS (bf16, per-wave private buffer) ----
    #pragma unroll
    for (int nt = 0; nt < 4; nt++)
      #pragma unroll
      for (int r = 0; r < 4; r++)
        uQP.p[wv][quad * 4 + r][nt * 16 + l15] = f2bf(sc[nt][r]);

    // rescale O while the P writes land
    #pragma unroll
    for (int dt = 0; dt < 8; dt++)
      #pragma unroll
      for (int r = 0; r < 4; r++)
        o_acc[dt][r] *= alpha[r];
    __syncthreads();

    // ---- O += P · V  (A = P from LDS in A-layout, B = Vt contiguous) ----
    bf16x8 ap[2];
    #pragma unroll
    for (int ks = 0; ks < 2; ks++)
      ap[ks] = *(const bf16x8*)&uQP.p[wv][l15][ks * 32 + quad * 8];
    #pragma unroll
    for (int dt = 0; dt < 8; dt++) {
      #pragma unroll
      for (int ks = 0; ks < 2; ks++) {
        const bf16x8 bv = *(const bf16x8*)&sVt[dt * 16 + l15][ks * 32 + quad * 8];
        o_acc[dt] = __builtin_amdgcn_mfma_f32_16x16x32_bf16(ap[ks], bv, o_acc[dt], 0, 0, 0);
      }
    }
    __syncthreads();   // protect sK/sVt/P before next iteration's staging
  }

  // ---------------- epilogue: normalize + coalesced store ----------------
  float* ob = og + ((size_t)(b * H_ + h) * S_ + q0) * D_;
  #pragma unroll
  for (int r = 0; r < 4; r++) {
    const float inv = 1.0f / l_i[r];
    const int row = wv * 16 + quad * 4 + r;
    #pragma unroll
    for (int dt = 0; dt < 8; dt++)
      ob[(size_t)row * D_ + dt * 16 + l15] = o_acc[dt][r] * inv;
  }
}

extern "C" void kernel_launch(void* const* d_in, const int* in_sizes, int n_in,
                              void* d_out, int out_size, void* d_ws, size_t ws_size,
                              hipStream_t stream) {
  const float* q = (const float*)d_in[0];
  const float* k = (const float*)d_in[1];
  const float* v = (const float*)d_in[2];
  const float* f = (const float*)d_in[3];
  float* o = (float*)d_out;

  dim3 grid(S_ / BQ, H_, B_);   // (32, 16, 2) = 1024 blocks
  dim3 block(256);
  fattn_rope<<<grid, block, 0, stream>>>(q, k, v, f, o);
}

// Round 2
// 299.034 us; speedup vs baseline: 1.5442x; 1.5442x over previous
//
#include <hip/hip_runtime.h>
#include <hip/hip_bf16.h>

// B=2, S=2048, H=16, D=128, fp32 in/out, causal, interleaved RoPE.
// Strategy: pass1 precomputes rope(Q)*scale, rope(K), V^T as bf16 in
// MFMA-fragment-ordered 16KB tiles in d_ws; pass2 is a flash-attention
// kernel staging via async global_load_lds (dual double-buffer, 1 barrier/iter).
#define B_  2
#define S_  2048
#define H_  16
#define D_  128
#define BQ  64
#define BK  64
#define SH  (H_ * D_)        // 2048
#define NT  (S_ / BK)        // 32 tiles per (b,h)
#define TILE_US 8192         // ushorts per 64x128 bf16 tile (16KB)

typedef __attribute__((ext_vector_type(8))) short bf16x8;
typedef __attribute__((ext_vector_type(4))) float f32x4;

__device__ __forceinline__ ushort f2bf(float x) {
  union { float f; unsigned u; } c; c.f = x;
  unsigned u = c.u;
  return (ushort)((u + 0x7FFFu + ((u >> 16) & 1u)) >> 16);
}

// async global->LDS, 16B per lane. LDS dst must be wave-uniform base + lane*16.
__device__ __forceinline__ void gload_lds16(const ushort* g, ushort* l) {
  __builtin_amdgcn_global_load_lds((const __attribute__((address_space(1))) void*)g,
                                   (__attribute__((address_space(3))) void*)l,
                                   16, 0, 0);
}

// ---------------------------------------------------------------------------
// Pass 1a: rope(Q)*QS and rope(K) -> bf16 tiles in fragment order.
// Tile unit u (16B, 8 ushorts): u = ks*256 + row*4 + quad; cols ks*32+quad*8+j.
// ---------------------------------------------------------------------------
__global__ __launch_bounds__(256)
void rope_qk_pack(const float* __restrict__ qg, const float* __restrict__ kg,
                  const float* __restrict__ fg,
                  ushort* __restrict__ qr, ushort* __restrict__ kr) {
  const int t = blockIdx.x, h = blockIdx.y, b = blockIdx.z;
  const int tid = threadIdx.x;
  const float QS = 0.08838834764831845f * 1.4426950408889634f; // 1/sqrt(128)*log2(e)
  const size_t tbase = ((size_t)(b * H_ + h) * NT + t) * TILE_US;

  #pragma unroll
  for (int c = 0; c < 4; c++) {
    const int u    = tid + 256 * c;
    const int ks   = u >> 8;
    const int rem  = u & 255;
    const int row  = rem >> 2;
    const int quad = rem & 3;
    const int col  = ks * 32 + quad * 8;
    const int s    = t * 64 + row;
    const size_t goff = ((size_t)(b * S_ + s)) * SH + (size_t)h * D_ + col;

    const float4 f0 = *(const float4*)(fg + (size_t)s * D_ + col);
    const float4 f1 = *(const float4*)(fg + (size_t)s * D_ + col + 4);
    const float4 qx0 = *(const float4*)(qg + goff);
    const float4 qx1 = *(const float4*)(qg + goff + 4);
    const float4 kx0 = *(const float4*)(kg + goff);
    const float4 kx1 = *(const float4*)(kg + goff + 4);

    union { ushort s[8]; uint4 v; } pq, pk;
    pq.s[0] = f2bf((f0.x*qx0.x - f0.y*qx0.y) * QS);
    pq.s[1] = f2bf((f0.y*qx0.x + f0.x*qx0.y) * QS);
    pq.s[2] = f2bf((f0.z*qx0.z - f0.w*qx0.w) * QS);
    pq.s[3] = f2bf((f0.w*qx0.z + f0.z*qx0.w) * QS);
    pq.s[4] = f2bf((f1.x*qx1.x - f1.y*qx1.y) * QS);
    pq.s[5] = f2bf((f1.y*qx1.x + f1.x*qx1.y) * QS);
    pq.s[6] = f2bf((f1.z*qx1.z - f1.w*qx1.w) * QS);
    pq.s[7] = f2bf((f1.w*qx1.z + f1.z*qx1.w) * QS);
    pk.s[0] = f2bf(f0.x*kx0.x - f0.y*kx0.y);
    pk.s[1] = f2bf(f0.y*kx0.x + f0.x*kx0.y);
    pk.s[2] = f2bf(f0.z*kx0.z - f0.w*kx0.w);
    pk.s[3] = f2bf(f0.w*kx0.z + f0.z*kx0.w);
    pk.s[4] = f2bf(f1.x*kx1.x - f1.y*kx1.y);
    pk.s[5] = f2bf(f1.y*kx1.x + f1.x*kx1.y);
    pk.s[6] = f2bf(f1.z*kx1.z - f1.w*kx1.w);
    pk.s[7] = f2bf(f1.w*kx1.z + f1.z*kx1.w);

    *(uint4*)(qr + tbase + (size_t)u * 8) = pq.v;
    *(uint4*)(kr + tbase + (size_t)u * 8) = pk.v;
  }
}

// ---------------------------------------------------------------------------
// Pass 1b: V^T bf16 tiles in fragment order (LDS transpose).
// Tile unit u: u = ks2*512 + dim*4 + quad; keys ks2*32+quad*8+j.
// ---------------------------------------------------------------------------
__global__ __launch_bounds__(256)
void vt_pack(const float* __restrict__ vg, ushort* __restrict__ vt) {
  __shared__ float sv[64][133];   // [key][dim], pad 133: 2-way read conflicts only
  const int t = blockIdx.x, h = blockIdx.y, b = blockIdx.z;
  const int tid = threadIdx.x;
  const size_t tbase = ((size_t)(b * H_ + h) * NT + t) * TILE_US;

  // coalesced load: 64 rows x 128 cols fp32
  #pragma unroll
  for (int c = 0; c < 8; c++) {
    const int f   = tid + 256 * c;        // float4 index, 0..2047
    const int row = f >> 5;
    const int c4  = (f & 31) * 4;
    const float4 x = *(const float4*)(vg + ((size_t)(b * S_ + t * 64 + row)) * SH
                                         + (size_t)h * D_ + c4);
    sv[row][c4 + 0] = x.x; sv[row][c4 + 1] = x.y;
    sv[row][c4 + 2] = x.z; sv[row][c4 + 3] = x.w;
  }
  __syncthreads();

  #pragma unroll
  for (int c = 0; c < 4; c++) {
    const int u    = tid + 256 * c;
    const int ks2  = u >> 9;
    const int rem  = u & 511;
    const int dim  = rem >> 2;
    const int quad = rem & 3;
    const int k0   = ks2 * 32 + quad * 8;
    union { ushort s[8]; uint4 v; } p;
    #pragma unroll
    for (int j = 0; j < 8; j++) p.s[j] = f2bf(sv[k0 + j][dim]);
    *(uint4*)(vt + tbase + (size_t)u * 8) = p.v;
  }
}

// ---------------------------------------------------------------------------
// Pass 2: flash attention. 4 waves, 16 q-rows/wave. Dual double-buffered
// async staging, 1 barrier per K-tile.
// ---------------------------------------------------------------------------
__global__ __launch_bounds__(256, 2)
void fattn2(const ushort* __restrict__ qr, const ushort* __restrict__ kr,
            const ushort* __restrict__ vt, float* __restrict__ og) {
  __shared__ __align__(16) ushort sK[2][TILE_US];
  __shared__ __align__(16) ushort sV[2][TILE_US];
  __shared__ __align__(16) ushort sP[4][16][72];   // wave-private P, stride 144B

  const int qt   = (int)gridDim.x - 1 - (int)blockIdx.x;  // heavy blocks first
  const int h    = blockIdx.y;
  const int b    = blockIdx.z;
  const int tid  = threadIdx.x;
  const int wv   = tid >> 6;
  const int lane = tid & 63;
  const int l15  = lane & 15;
  const int quad = lane >> 4;

  const ushort* ktb = kr + ((size_t)(b * H_ + h) * NT) * TILE_US;
  const ushort* vtb = vt + ((size_t)(b * H_ + h) * NT) * TILE_US;
  const ushort* qtb = qr + ((size_t)(b * H_ + h) * NT + qt) * TILE_US;

  // Q fragments straight from global (fragment-ordered tile)
  bf16x8 afq[4];
  #pragma unroll
  for (int ks = 0; ks < 4; ks++)
    afq[ks] = *(const bf16x8*)(qtb + (size_t)(ks * 256 + (wv * 16 + l15) * 4 + quad) * 8);

  float m_i[4], l_i[4];
  f32x4 o_acc[8];
  #pragma unroll
  for (int r = 0; r < 4; r++) { m_i[r] = -1e30f; l_i[r] = 0.0f; }
  #pragma unroll
  for (int dt = 0; dt < 8; dt++) o_acc[dt] = (f32x4)0.0f;

  // prologue: stage tile 0 into buffer 0 (16 x 1KB instrs each for K and V)
  {
    const ushort* ksrc = ktb;           // kt=0
    const ushort* vsrc = vtb;
    #pragma unroll
    for (int c = 0; c < 4; c++) {
      const int g = wv * 4 + c;
      gload_lds16(ksrc + g * 512 + lane * 8, &sK[0][g * 512 + lane * 8]);
      gload_lds16(vsrc + g * 512 + lane * 8, &sV[0][g * 512 + lane * 8]);
    }
  }

  int buf = 0;
  for (int kt = 0; kt <= qt; kt++) {
    __syncthreads();   // drains async loads -> tile kt ready in buf

    // async prefetch tile kt+1 into the other buffer; overlaps all compute below
    if (kt < qt) {
      const ushort* ksrc = ktb + (size_t)(kt + 1) * TILE_US;
      const ushort* vsrc = vtb + (size_t)(kt + 1) * TILE_US;
      #pragma unroll
      for (int c = 0; c < 4; c++) {
        const int g = wv * 4 + c;
        gload_lds16(ksrc + g * 512 + lane * 8, &sK[buf ^ 1][g * 512 + lane * 8]);
        gload_lds16(vsrc + g * 512 + lane * 8, &sV[buf ^ 1][g * 512 + lane * 8]);
      }
    }

    // ---- S = Qs · K^T (16x64 per wave) ----
    f32x4 sc[4];
    #pragma unroll
    for (int nt = 0; nt < 4; nt++) {
      f32x4 acc = (f32x4)0.0f;
      #pragma unroll
      for (int ks = 0; ks < 4; ks++) {
        const bf16x8 bk_ = *(const bf16x8*)&sK[buf][(ks * 256 + (nt * 16 + l15) * 4 + quad) * 8];
        acc = __builtin_amdgcn_mfma_f32_16x16x32_bf16(afq[ks], bk_, acc, 0, 0, 0);
      }
      sc[nt] = acc;
    }

    // ---- causal mask on diagonal tile ----
    if (kt == qt) {
      #pragma unroll
      for (int nt = 0; nt < 4; nt++) {
        const int col = nt * 16 + l15;
        #pragma unroll
        for (int r = 0; r < 4; r++) {
          const int row = wv * 16 + quad * 4 + r;
          if (col > row) sc[nt][r] = -1e30f;
        }
      }
    }

    // ---- online softmax (exp2 domain) ----
    float mnew[4], alpha[4];
    #pragma unroll
    for (int r = 0; r < 4; r++) {
      float mx = fmaxf(fmaxf(sc[0][r], sc[1][r]), fmaxf(sc[2][r], sc[3][r]));
      mx = fmaxf(mx, __shfl_xor(mx, 1));
      mx = fmaxf(mx, __shfl_xor(mx, 2));
      mx = fmaxf(mx, __shfl_xor(mx, 4));
      mx = fmaxf(mx, __shfl_xor(mx, 8));
      mnew[r]  = fmaxf(m_i[r], mx);
      alpha[r] = __builtin_amdgcn_exp2f(m_i[r] - mnew[r]);
      m_i[r]   = mnew[r];
    }
    float rs[4] = {0.0f, 0.0f, 0.0f, 0.0f};
    #pragma unroll
    for (int nt = 0; nt < 4; nt++) {
      #pragma unroll
      for (int r = 0; r < 4; r++) {
        const float p = __builtin_amdgcn_exp2f(sc[nt][r] - mnew[r]);
        sc[nt][r] = p;
        rs[r] += p;
      }
    }
    #pragma unroll
    for (int r = 0; r < 4; r++) {
      float t = rs[r];
      t += __shfl_xor(t, 1);
      t += __shfl_xor(t, 2);
      t += __shfl_xor(t, 4);
      t += __shfl_xor(t, 8);
      l_i[r] = l_i[r] * alpha[r] + t;
    }

    // ---- P: C-layout -> wave-private LDS (no barrier needed) ----
    #pragma unroll
    for (int nt = 0; nt < 4; nt++)
      #pragma unroll
      for (int r = 0; r < 4; r++)
        sP[wv][quad * 4 + r][nt * 16 + l15] = f2bf(sc[nt][r]);

    #pragma unroll
    for (int dt = 0; dt < 8; dt++)
      #pragma unroll
      for (int r = 0; r < 4; r++)
        o_acc[dt][r] *= alpha[r];

    // ---- O += P · V ----
    bf16x8 ap[2];
    #pragma unroll
    for (int ks = 0; ks < 2; ks++)
      ap[ks] = *(const bf16x8*)&sP[wv][l15][ks * 32 + quad * 8];
    #pragma unroll
    for (int dt = 0; dt < 8; dt++) {
      #pragma unroll
      for (int ks = 0; ks < 2; ks++) {
        const bf16x8 bv = *(const bf16x8*)&sV[buf][(ks * 512 + (dt * 16 + l15) * 4 + quad) * 8];
        o_acc[dt] = __builtin_amdgcn_mfma_f32_16x16x32_bf16(ap[ks], bv, o_acc[dt], 0, 0, 0);
      }
    }

    buf ^= 1;
  }

  // ---- epilogue ----
  float* ob = og + ((size_t)(b * H_ + h) * S_ + (size_t)qt * BQ) * D_;
  #pragma unroll
  for (int r = 0; r < 4; r++) {
    const float inv = 1.0f / l_i[r];
    const int row = wv * 16 + quad * 4 + r;
    #pragma unroll
    for (int dt = 0; dt < 8; dt++)
      ob[(size_t)row * D_ + dt * 16 + l15] = o_acc[dt][r] * inv;
  }
}

extern "C" void kernel_launch(void* const* d_in, const int* in_sizes, int n_in,
                              void* d_out, int out_size, void* d_ws, size_t ws_size,
                              hipStream_t stream) {
  const float* q = (const float*)d_in[0];
  const float* k = (const float*)d_in[1];
  const float* v = (const float*)d_in[2];
  const float* f = (const float*)d_in[3];
  float* o = (float*)d_out;

  const size_t NELT = (size_t)B_ * S_ * H_ * D_;   // 8388608
  ushort* qr = (ushort*)d_ws;
  ushort* kr = qr + NELT;
  ushort* vt = kr + NELT;

  dim3 grid(NT, H_, B_);    // (32,16,2)
  dim3 block(256);
  rope_qk_pack<<<grid, block, 0, stream>>>(q, k, f, qr, kr);
  vt_pack<<<grid, block, 0, stream>>>(v, vt);
  fattn2<<<grid, block, 0, stream>>>(qr, kr, vt, o);
}

// Round 3
// 238.703 us; speedup vs baseline: 1.9345x; 1.2527x over previous
//
#include <hip/hip_runtime.h>
#include <hip/hip_bf16.h>

// B=2, S=2048, H=16, D=128, fp32 in/out, causal, interleaved RoPE.
// pass1 (pack_all): rope(Q)*scale*log2e, rope(K), V^T as bf16 tiles in
// LANE-LINEAR fragment order (group*1024B + lane*16B) in d_ws.
// pass2 (fattn3): flash attention, max-free exp2 softmax, dual double-buffered
// global_load_lds staging, 1 barrier/iter, conflict-free LDS reads.
#define B_  2
#define S_  2048
#define H_  16
#define D_  128
#define BQ  64
#define BK  64
#define SH  (H_ * D_)        // 2048
#define NT  (S_ / BK)        // 32 tiles per (b,h)
#define TILE_US 8192         // ushorts per 64x128 bf16 tile (16KB)

typedef __attribute__((ext_vector_type(8))) short bf16x8;
typedef __attribute__((ext_vector_type(4))) float f32x4;

__device__ __forceinline__ ushort f2bf(float x) {
  union { float f; unsigned u; } c; c.f = x;
  unsigned u = c.u;
  return (ushort)((u + 0x7FFFu + ((u >> 16) & 1u)) >> 16);
}

// async global->LDS, 16B per lane; LDS dst = wave-uniform base + lane*16.
__device__ __forceinline__ void gload_lds16(const ushort* g, ushort* l) {
  __builtin_amdgcn_global_load_lds((const __attribute__((address_space(1))) void*)g,
                                   (__attribute__((address_space(3))) void*)l,
                                   16, 0, 0);
}

// ---------------------------------------------------------------------------
// Pass 1: one kernel packs rope(Q)*QS, rope(K), V^T.
// K/Q tile (64 rows x 128 cols): unit = (ks*4+rb)*64 + ((row&15)|(((col>>3)&3)<<4))
//   -> wave reading fragment (ks, rb-block) gets unit = group*64 + lane (linear).
// V^T tile (128 dims x 64 keys): unit = (ks2*8+db)*64 + ((dim&15)|(((key>>3)&3)<<4))
// ---------------------------------------------------------------------------
__global__ __launch_bounds__(256)
void pack_all(const float* __restrict__ qg, const float* __restrict__ kg,
              const float* __restrict__ vg, const float* __restrict__ fg,
              ushort* __restrict__ qr, ushort* __restrict__ kr,
              ushort* __restrict__ vt) {
  __shared__ float sv[64][133];   // pad 133: 2-way (free) on transpose reads
  const int t = blockIdx.x, h = blockIdx.y, b = blockIdx.z;
  const int tid = threadIdx.x;
  const float QS = 0.08838834764831845f * 1.4426950408889634f; // 1/sqrt(128)*log2(e)
  const size_t tbase = ((size_t)(b * H_ + h) * NT + t) * TILE_US;

  #pragma unroll
  for (int c = 0; c < 4; c++) {
    const int idx = tid + 256 * c;   // 0..1023
    const int row = idx >> 4;        // 0..63
    const int cu  = idx & 15;        // 8-col unit; wave covers 512B/row contiguous
    const int col = cu * 8;
    const int s   = t * 64 + row;
    const size_t goff = ((size_t)(b * S_ + s)) * SH + (size_t)h * D_ + col;

    const float4 f0 = *(const float4*)(fg + (size_t)s * D_ + col);
    const float4 f1 = *(const float4*)(fg + (size_t)s * D_ + col + 4);
    const float4 qx0 = *(const float4*)(qg + goff);
    const float4 qx1 = *(const float4*)(qg + goff + 4);
    const float4 kx0 = *(const float4*)(kg + goff);
    const float4 kx1 = *(const float4*)(kg + goff + 4);
    const float4 vx0 = *(const float4*)(vg + goff);
    const float4 vx1 = *(const float4*)(vg + goff + 4);

    *(float4*)&sv[row][col]     = vx0;
    *(float4*)&sv[row][col + 4] = vx1;

    union { ushort s[8]; uint4 v; } pq, pk;
    pq.s[0] = f2bf((f0.x*qx0.x - f0.y*qx0.y) * QS);
    pq.s[1] = f2bf((f0.y*qx0.x + f0.x*qx0.y) * QS);
    pq.s[2] = f2bf((f0.z*qx0.z - f0.w*qx0.w) * QS);
    pq.s[3] = f2bf((f0.w*qx0.z + f0.z*qx0.w) * QS);
    pq.s[4] = f2bf((f1.x*qx1.x - f1.y*qx1.y) * QS);
    pq.s[5] = f2bf((f1.y*qx1.x + f1.x*qx1.y) * QS);
    pq.s[6] = f2bf((f1.z*qx1.z - f1.w*qx1.w) * QS);
    pq.s[7] = f2bf((f1.w*qx1.z + f1.z*qx1.w) * QS);
    pk.s[0] = f2bf(f0.x*kx0.x - f0.y*kx0.y);
    pk.s[1] = f2bf(f0.y*kx0.x + f0.x*kx0.y);
    pk.s[2] = f2bf(f0.z*kx0.z - f0.w*kx0.w);
    pk.s[3] = f2bf(f0.w*kx0.z + f0.z*kx0.w);
    pk.s[4] = f2bf(f1.x*kx1.x - f1.y*kx1.y);
    pk.s[5] = f2bf(f1.y*kx1.x + f1.x*kx1.y);
    pk.s[6] = f2bf(f1.z*kx1.z - f1.w*kx1.w);
    pk.s[7] = f2bf(f1.w*kx1.z + f1.z*kx1.w);

    // lane-linear fragment position
    const int pos = ((cu >> 2) * 4 + (row >> 4)) * 64 + ((row & 15) | ((cu & 3) << 4));
    *(uint4*)(qr + tbase + (size_t)pos * 8) = pq.v;
    *(uint4*)(kr + tbase + (size_t)pos * 8) = pk.v;
  }
  __syncthreads();

  // V^T in lane-linear fragment order, coalesced 16B writes
  #pragma unroll
  for (int c = 0; c < 4; c++) {
    const int u2  = tid + 256 * c;     // = group*64 + lane
    const int g2  = u2 >> 6;
    const int ln  = u2 & 63;
    const int dim = (g2 & 7) * 16 + (ln & 15);
    const int k0  = (g2 >> 3) * 32 + (ln >> 4) * 8;
    union { ushort s[8]; uint4 v; } p;
    #pragma unroll
    for (int j = 0; j < 8; j++) p.s[j] = f2bf(sv[k0 + j][dim]);
    *(uint4*)(vt + tbase + (size_t)u2 * 8) = p.v;
  }
}

// ---------------------------------------------------------------------------
// Pass 2: flash attention, max-free softmax, 1 barrier per K-tile.
// ---------------------------------------------------------------------------
__global__ __launch_bounds__(256, 2)
void fattn3(const ushort* __restrict__ qr, const ushort* __restrict__ kr,
            const ushort* __restrict__ vt, float* __restrict__ og) {
  __shared__ __align__(16) ushort sK[2][TILE_US];
  __shared__ __align__(16) ushort sV[2][TILE_US];
  __shared__ __align__(16) ushort sP[4][1024];   // wave-private P (16x64 bf16)

  const int qt   = (int)gridDim.x - 1 - (int)blockIdx.x;  // heavy blocks first
  const int h    = blockIdx.y;
  const int b    = blockIdx.z;
  const int tid  = threadIdx.x;
  const int wv   = tid >> 6;
  const int lane = tid & 63;
  const int l15  = lane & 15;
  const int quad = lane >> 4;

  const ushort* ktb = kr + ((size_t)(b * H_ + h) * NT) * TILE_US;
  const ushort* vtb = vt + ((size_t)(b * H_ + h) * NT) * TILE_US;
  const ushort* qtb = qr + ((size_t)(b * H_ + h) * NT + qt) * TILE_US;

  // Q fragments from global: group (ks*4+wv), lane-linear -> coalesced
  bf16x8 afq[4];
  #pragma unroll
  for (int ks = 0; ks < 4; ks++)
    afq[ks] = *(const bf16x8*)(qtb + (size_t)((ks * 4 + wv) * 64 + lane) * 8);

  float rs[4] = {0.0f, 0.0f, 0.0f, 0.0f};   // per-lane row-sum partials
  f32x4 o_acc[8];                            // un-normalized O
  #pragma unroll
  for (int dt = 0; dt < 8; dt++) o_acc[dt] = (f32x4)0.0f;

  // prologue: stage tile 0 into buffer 0
  #pragma unroll
  for (int c = 0; c < 4; c++) {
    const int g = wv * 4 + c;
    gload_lds16(ktb + g * 512 + lane * 8, &sK[0][g * 512 + lane * 8]);
    gload_lds16(vtb + g * 512 + lane * 8, &sV[0][g * 512 + lane * 8]);
  }

  int buf = 0;
  for (int kt = 0; kt <= qt; kt++) {
    __syncthreads();   // drains prefetch issued one full iteration ago

    if (kt < qt) {
      const ushort* ksrc = ktb + (size_t)(kt + 1) * TILE_US;
      const ushort* vsrc = vtb + (size_t)(kt + 1) * TILE_US;
      #pragma unroll
      for (int c = 0; c < 4; c++) {
        const int g = wv * 4 + c;
        gload_lds16(ksrc + g * 512 + lane * 8, &sK[buf ^ 1][g * 512 + lane * 8]);
        gload_lds16(vsrc + g * 512 + lane * 8, &sV[buf ^ 1][g * 512 + lane * 8]);
      }
    }

    // ---- S = Qs · K^T (16x64 per wave), conflict-free lane-linear reads ----
    f32x4 sc[4];
    #pragma unroll
    for (int nt = 0; nt < 4; nt++) {
      f32x4 acc = (f32x4)0.0f;
      #pragma unroll
      for (int ks = 0; ks < 4; ks++) {
        const bf16x8 bk_ = *(const bf16x8*)&sK[buf][(size_t)((ks * 4 + nt) * 64 + lane) * 8];
        acc = __builtin_amdgcn_mfma_f32_16x16x32_bf16(afq[ks], bk_, acc, 0, 0, 0);
      }
      sc[nt] = acc;
    }

    // ---- causal mask on diagonal tile ----
    if (kt == qt) {
      #pragma unroll
      for (int nt = 0; nt < 4; nt++) {
        const int col = nt * 16 + l15;
        #pragma unroll
        for (int r = 0; r < 4; r++) {
          const int row = wv * 16 + quad * 4 + r;
          if (col > row) sc[nt][r] = -1e30f;
        }
      }
    }

    // ---- max-free softmax: p = exp2(s); accumulate row-sum partials ----
    #pragma unroll
    for (int nt = 0; nt < 4; nt++) {
      #pragma unroll
      for (int r = 0; r < 4; r++) {
        const float p = __builtin_amdgcn_exp2f(sc[nt][r]);
        sc[nt][r] = p;
        rs[r] += p;
      }
    }

    // ---- P: C-layout -> wave-private LDS in lane-linear fragment order ----
    // element (row,key): idx = (key>>5)*512 + row*8 + ((key>>3)&3)*128 + (key&7)
    #pragma unroll
    for (int nt = 0; nt < 4; nt++) {
      const int kk = ((nt & 1) << 1) | (l15 >> 3);
      const int base = (nt >> 1) * 512 + kk * 128 + (l15 & 7);
      #pragma unroll
      for (int r = 0; r < 4; r++)
        sP[wv][base + (quad * 4 + r) * 8] = f2bf(sc[nt][r]);
    }

    // ---- O += P · V  (lane-linear reads, no barrier: wave-private P) ----
    bf16x8 ap[2];
    #pragma unroll
    for (int ks = 0; ks < 2; ks++)
      ap[ks] = *(const bf16x8*)&sP[wv][(size_t)(ks * 64 + lane) * 8];
    #pragma unroll
    for (int dt = 0; dt < 8; dt++) {
      #pragma unroll
      for (int ks = 0; ks < 2; ks++) {
        const bf16x8 bv = *(const bf16x8*)&sV[buf][(size_t)((ks * 8 + dt) * 64 + lane) * 8];
        o_acc[dt] = __builtin_amdgcn_mfma_f32_16x16x32_bf16(ap[ks], bv, o_acc[dt], 0, 0, 0);
      }
    }

    buf ^= 1;
  }

  // ---- epilogue: one deferred row-sum reduction, normalize, store ----
  float* ob = og + ((size_t)(b * H_ + h) * S_ + (size_t)qt * BQ) * D_;
  #pragma unroll
  for (int r = 0; r < 4; r++) {
    float t = rs[r];
    t += __shfl_xor(t, 1);
    t += __shfl_xor(t, 2);
    t += __shfl_xor(t, 4);
    t += __shfl_xor(t, 8);
    const float inv = 1.0f / t;
    const int row = wv * 16 + quad * 4 + r;
    #pragma unroll
    for (int dt = 0; dt < 8; dt++)
      ob[(size_t)row * D_ + dt * 16 + l15] = o_acc[dt][r] * inv;
  }
}

extern "C" void kernel_launch(void* const* d_in, const int* in_sizes, int n_in,
                              void* d_out, int out_size, void* d_ws, size_t ws_size,
                              hipStream_t stream) {
  const float* q = (const float*)d_in[0];
  const float* k = (const float*)d_in[1];
  const float* v = (const float*)d_in[2];
  const float* f = (const float*)d_in[3];
  float* o = (float*)d_out;

  const size_t NELT = (size_t)B_ * S_ * H_ * D_;   // 8388608
  ushort* qr = (ushort*)d_ws;
  ushort* kr = qr + NELT;
  ushort* vt = kr + NELT;

  dim3 grid(NT, H_, B_);    // (32,16,2) = 1024 blocks
  dim3 block(256);
  pack_all<<<grid, block, 0, stream>>>(q, k, v, f, qr, kr, vt);
  fattn3<<<grid, block, 0, stream>>>(qr, kr, vt, o);
}

// Round 4
// 214.186 us; speedup vs baseline: 2.1559x; 1.1145x over previous
//
#include <hip/hip_runtime.h>
#include <hip/hip_bf16.h>

// B=2, S=2048, H=16, D=128, fp32 in/out, causal, interleaved RoPE.
// pass1 (pack_all): rope(Q)*scale*log2e, rope(K), V^T as bf16 in lane-linear
// fragment-ordered 64x128 tiles (group*1024B + lane*16B) in d_ws.
// pass2 (fattn4): flash attention, BQ=128 (4 waves x 32 q-rows -> halved LDS
// K/V re-reads), max-free exp2 softmax, dual double-buffered global_load_lds
// staging, 1 barrier/iter, conflict-free b128 LDS reads.
#define B_  2
#define S_  2048
#define H_  16
#define D_  128
#define BQ  128
#define BK  64
#define SH  (H_ * D_)        // 2048
#define NT  (S_ / 64)        // 32 pack tiles (64 rows each) per (b,h)
#define NTQ (S_ / BQ)        // 16 q-blocks per (b,h)
#define TILE_US 8192         // ushorts per 64x128 bf16 tile (16KB)

typedef __attribute__((ext_vector_type(8))) short bf16x8;
typedef __attribute__((ext_vector_type(4))) float f32x4;

__device__ __forceinline__ ushort f2bf(float x) {
  union { float f; unsigned u; } c; c.f = x;
  unsigned u = c.u;
  return (ushort)((u + 0x7FFFu + ((u >> 16) & 1u)) >> 16);
}

// async global->LDS, 16B per lane; LDS dst = wave-uniform base + lane*16.
__device__ __forceinline__ void gload_lds16(const ushort* g, ushort* l) {
  __builtin_amdgcn_global_load_lds((const __attribute__((address_space(1))) void*)g,
                                   (__attribute__((address_space(3))) void*)l,
                                   16, 0, 0);
}

// ---------------------------------------------------------------------------
// Pass 1: packs rope(Q)*QS, rope(K), V^T into lane-linear fragment tiles.
// K/Q tile: pos = ((col>>5)*4 + (row>>4))*64 + ((row&15) | (((col>>3)&3)<<4))
// V^T tile: pos = ((ks2*8+db)*64) + ((dim&15) | (((key>>3)&3)<<4))
// ---------------------------------------------------------------------------
__global__ __launch_bounds__(256)
void pack_all(const float* __restrict__ qg, const float* __restrict__ kg,
              const float* __restrict__ vg, const float* __restrict__ fg,
              ushort* __restrict__ qr, ushort* __restrict__ kr,
              ushort* __restrict__ vt) {
  __shared__ float sv[64][133];
  const int t = blockIdx.x, h = blockIdx.y, b = blockIdx.z;
  const int tid = threadIdx.x;
  const float QS = 0.08838834764831845f * 1.4426950408889634f; // 1/sqrt(128)*log2(e)
  const size_t tbase = ((size_t)(b * H_ + h) * NT + t) * TILE_US;

  #pragma unroll
  for (int c = 0; c < 4; c++) {
    const int idx = tid + 256 * c;   // 0..1023
    const int row = idx >> 4;
    const int cu  = idx & 15;
    const int col = cu * 8;
    const int s   = t * 64 + row;
    const size_t goff = ((size_t)(b * S_ + s)) * SH + (size_t)h * D_ + col;

    const float4 f0 = *(const float4*)(fg + (size_t)s * D_ + col);
    const float4 f1 = *(const float4*)(fg + (size_t)s * D_ + col + 4);
    const float4 qx0 = *(const float4*)(qg + goff);
    const float4 qx1 = *(const float4*)(qg + goff + 4);
    const float4 kx0 = *(const float4*)(kg + goff);
    const float4 kx1 = *(const float4*)(kg + goff + 4);
    const float4 vx0 = *(const float4*)(vg + goff);
    const float4 vx1 = *(const float4*)(vg + goff + 4);

    *(float4*)&sv[row][col]     = vx0;
    *(float4*)&sv[row][col + 4] = vx1;

    union { ushort s[8]; uint4 v; } pq, pk;
    pq.s[0] = f2bf((f0.x*qx0.x - f0.y*qx0.y) * QS);
    pq.s[1] = f2bf((f0.y*qx0.x + f0.x*qx0.y) * QS);
    pq.s[2] = f2bf((f0.z*qx0.z - f0.w*qx0.w) * QS);
    pq.s[3] = f2bf((f0.w*qx0.z + f0.z*qx0.w) * QS);
    pq.s[4] = f2bf((f1.x*qx1.x - f1.y*qx1.y) * QS);
    pq.s[5] = f2bf((f1.y*qx1.x + f1.x*qx1.y) * QS);
    pq.s[6] = f2bf((f1.z*qx1.z - f1.w*qx1.w) * QS);
    pq.s[7] = f2bf((f1.w*qx1.z + f1.z*qx1.w) * QS);
    pk.s[0] = f2bf(f0.x*kx0.x - f0.y*kx0.y);
    pk.s[1] = f2bf(f0.y*kx0.x + f0.x*kx0.y);
    pk.s[2] = f2bf(f0.z*kx0.z - f0.w*kx0.w);
    pk.s[3] = f2bf(f0.w*kx0.z + f0.z*kx0.w);
    pk.s[4] = f2bf(f1.x*kx1.x - f1.y*kx1.y);
    pk.s[5] = f2bf(f1.y*kx1.x + f1.x*kx1.y);
    pk.s[6] = f2bf(f1.z*kx1.z - f1.w*kx1.w);
    pk.s[7] = f2bf(f1.w*kx1.z + f1.z*kx1.w);

    const int pos = ((cu >> 2) * 4 + (row >> 4)) * 64 + ((row & 15) | ((cu & 3) << 4));
    *(uint4*)(qr + tbase + (size_t)pos * 8) = pq.v;
    *(uint4*)(kr + tbase + (size_t)pos * 8) = pk.v;
  }
  __syncthreads();

  #pragma unroll
  for (int c = 0; c < 4; c++) {
    const int u2  = tid + 256 * c;     // = group*64 + lane
    const int g2  = u2 >> 6;
    const int ln  = u2 & 63;
    const int dim = (g2 & 7) * 16 + (ln & 15);
    const int k0  = (g2 >> 3) * 32 + (ln >> 4) * 8;
    union { ushort s[8]; uint4 v; } p;
    #pragma unroll
    for (int j = 0; j < 8; j++) p.s[j] = f2bf(sv[k0 + j][dim]);
    *(uint4*)(vt + tbase + (size_t)u2 * 8) = p.v;
  }
}

// ---------------------------------------------------------------------------
// Pass 2: flash attention, 4 waves x 32 q-rows, max-free softmax.
// ---------------------------------------------------------------------------
__global__ __launch_bounds__(256, 2)
void fattn4(const ushort* __restrict__ qr, const ushort* __restrict__ kr,
            const ushort* __restrict__ vt, float* __restrict__ og) {
  __shared__ __align__(16) ushort sK[2][TILE_US];
  __shared__ __align__(16) ushort sV[2][TILE_US];
  __shared__ __align__(16) ushort sP[4][2048];   // wave-private P (32x64 bf16)

  const int qt   = NTQ - 1 - (int)blockIdx.x;    // heavy blocks first
  const int h    = blockIdx.y;
  const int b    = blockIdx.z;
  const int tid  = threadIdx.x;
  const int wv   = tid >> 6;
  const int lane = tid & 63;
  const int l15  = lane & 15;
  const int quad = lane >> 4;

  const size_t bh = (size_t)(b * H_ + h);
  const ushort* ktb = kr + bh * NT * TILE_US;
  const ushort* vtb = vt + bh * NT * TILE_US;

  // Q fragments: wave wv covers q-rows [wv*32, wv*32+32) of the 128-row block.
  // Row-half rh (16 rows) lives in pack tile 2qt+(wv>>1), row-block (wv&1)*2+rh.
  bf16x8 afq[2][4];
  {
    const ushort* qtb64 = qr + (bh * NT + 2 * qt + (wv >> 1)) * TILE_US;
    const int rbb = (wv & 1) * 2;
    #pragma unroll
    for (int rh = 0; rh < 2; rh++)
      #pragma unroll
      for (int ks = 0; ks < 4; ks++)
        afq[rh][ks] = *(const bf16x8*)(qtb64 + (size_t)((ks * 4 + rbb + rh) * 64 + lane) * 8);
  }

  float rs[2][4];
  f32x4 o_acc[2][8];
  #pragma unroll
  for (int rh = 0; rh < 2; rh++) {
    #pragma unroll
    for (int r = 0; r < 4; r++) rs[rh][r] = 0.0f;
    #pragma unroll
    for (int dt = 0; dt < 8; dt++) o_acc[rh][dt] = (f32x4)0.0f;
  }

  // prologue: stage K/V tile 0 into buffer 0
  #pragma unroll
  for (int c = 0; c < 4; c++) {
    const int g = wv * 4 + c;
    gload_lds16(ktb + g * 512 + lane * 8, &sK[0][g * 512 + lane * 8]);
    gload_lds16(vtb + g * 512 + lane * 8, &sV[0][g * 512 + lane * 8]);
  }

  const int nkt = 2 * qt + 2;
  int buf = 0;
  for (int kt = 0; kt < nkt; kt++) {
    __syncthreads();   // drains prefetch issued one full iteration ago

    if (kt + 1 < nkt) {
      const ushort* ksrc = ktb + (size_t)(kt + 1) * TILE_US;
      const ushort* vsrc = vtb + (size_t)(kt + 1) * TILE_US;
      #pragma unroll
      for (int c = 0; c < 4; c++) {
        const int g = wv * 4 + c;
        gload_lds16(ksrc + g * 512 + lane * 8, &sK[buf ^ 1][g * 512 + lane * 8]);
        gload_lds16(vsrc + g * 512 + lane * 8, &sV[buf ^ 1][g * 512 + lane * 8]);
      }
    }

    // ---- S = Qs·K^T : 32x64 per wave; each K frag read once, used 2x ----
    f32x4 sc[2][4];
    #pragma unroll
    for (int rh = 0; rh < 2; rh++)
      #pragma unroll
      for (int nt = 0; nt < 4; nt++) sc[rh][nt] = (f32x4)0.0f;
    #pragma unroll
    for (int nt = 0; nt < 4; nt++) {
      #pragma unroll
      for (int ks = 0; ks < 4; ks++) {
        const bf16x8 bk_ = *(const bf16x8*)&sK[buf][(size_t)((ks * 4 + nt) * 64 + lane) * 8];
        sc[0][nt] = __builtin_amdgcn_mfma_f32_16x16x32_bf16(afq[0][ks], bk_, sc[0][nt], 0, 0, 0);
        sc[1][nt] = __builtin_amdgcn_mfma_f32_16x16x32_bf16(afq[1][ks], bk_, sc[1][nt], 0, 0, 0);
      }
    }

    // ---- causal mask (only the last two tiles can cross the diagonal) ----
    if (kt >= 2 * qt) {
      #pragma unroll
      for (int rh = 0; rh < 2; rh++) {
        #pragma unroll
        for (int nt = 0; nt < 4; nt++) {
          const int col = kt * 64 + nt * 16 + l15;
          #pragma unroll
          for (int r = 0; r < 4; r++) {
            const int row = qt * 128 + wv * 32 + rh * 16 + quad * 4 + r;
            if (col > row) sc[rh][nt][r] = -1e30f;
          }
        }
      }
    }

    // ---- max-free softmax + P pack into wave-private LDS ----
    #pragma unroll
    for (int rh = 0; rh < 2; rh++) {
      #pragma unroll
      for (int nt = 0; nt < 4; nt++) {
        const int base = rh * 1024 + (nt >> 1) * 512
                       + (((nt & 1) << 1) | (l15 >> 3)) * 128 + (l15 & 7);
        #pragma unroll
        for (int r = 0; r < 4; r++) {
          const float p = __builtin_amdgcn_exp2f(sc[rh][nt][r]);
          rs[rh][r] += p;
          sP[wv][base + (quad * 4 + r) * 8] = f2bf(p);
        }
      }
    }

    // ---- O += P·V : each V frag read once, used 2x ----
    bf16x8 ap[2][2];
    #pragma unroll
    for (int rh = 0; rh < 2; rh++)
      #pragma unroll
      for (int ks = 0; ks < 2; ks++)
        ap[rh][ks] = *(const bf16x8*)&sP[wv][(size_t)(rh * 1024 + (ks * 64 + lane) * 8)];
    #pragma unroll
    for (int dt = 0; dt < 8; dt++) {
      #pragma unroll
      for (int ks = 0; ks < 2; ks++) {
        const bf16x8 bv = *(const bf16x8*)&sV[buf][(size_t)((ks * 8 + dt) * 64 + lane) * 8];
        o_acc[0][dt] = __builtin_amdgcn_mfma_f32_16x16x32_bf16(ap[0][ks], bv, o_acc[0][dt], 0, 0, 0);
        o_acc[1][dt] = __builtin_amdgcn_mfma_f32_16x16x32_bf16(ap[1][ks], bv, o_acc[1][dt], 0, 0, 0);
      }
    }

    buf ^= 1;
  }

  // ---- epilogue: deferred row-sum reduction, normalize, store ----
  float* ob = og + (bh * S_ + (size_t)qt * BQ) * D_;
  #pragma unroll
  for (int rh = 0; rh < 2; rh++) {
    #pragma unroll
    for (int r = 0; r < 4; r++) {
      float t = rs[rh][r];
      t += __shfl_xor(t, 1);
      t += __shfl_xor(t, 2);
      t += __shfl_xor(t, 4);
      t += __shfl_xor(t, 8);
      const float inv = 1.0f / t;
      const int row = wv * 32 + rh * 16 + quad * 4 + r;
      #pragma unroll
      for (int dt = 0; dt < 8; dt++)
        ob[(size_t)row * D_ + dt * 16 + l15] = o_acc[rh][dt][r] * inv;
    }
  }
}

extern "C" void kernel_launch(void* const* d_in, const int* in_sizes, int n_in,
                              void* d_out, int out_size, void* d_ws, size_t ws_size,
                              hipStream_t stream) {
  const float* q = (const float*)d_in[0];
  const float* k = (const float*)d_in[1];
  const float* v = (const float*)d_in[2];
  const float* f = (const float*)d_in[3];
  float* o = (float*)d_out;

  const size_t NELT = (size_t)B_ * S_ * H_ * D_;   // 8388608
  ushort* qr = (ushort*)d_ws;
  ushort* kr = qr + NELT;
  ushort* vt = kr + NELT;

  dim3 block(256);
  pack_all<<<dim3(NT, H_, B_), block, 0, stream>>>(q, k, v, f, qr, kr, vt);
  fattn4<<<dim3(NTQ, H_, B_), block, 0, stream>>>(qr, kr, vt, o);
}